// Round 2
// baseline (254.184 us; speedup 1.0000x reference)
//
#include <hip/hip_runtime.h>

#define NCLU 32
#define NDIM 16
#define W_VAR 3.0f
#define W_DIST 1.0f
#define W_REG 0.001f
#define W_SMOOTH 5.0f
#define W_SEED 5.0f

// ws float-index layout ([0,4) = two doubles acc[0]=bce, acc[1]=seed)
enum {
    F_CNT  = 4,            // [4,36)    counts
    F_SV   = 36,           // [36,68)   sum v
    F_SV2  = 68,           // [68,100)  sum v^2
    F_SF   = 100,          // [100,612) sum features [c*16+d]
    F_CM   = 612,          // [612,1124) cluster means
    F_M2   = 1124,         // [1124,1156) |mean|^2
    F_I2V  = 1156,         // [1156,1188) +1/(2 var)  (positive)
    F_SMALL= 1188,         // dist+reg+smooth (weighted)
    F_END  = 1192
};

#define RREP 8
#define CSTRIDE 20                      // 19 slots + 1 pad
#define RSTRIDE (NCLU * CSTRIDE + 8)    // 648: replica bank rotation

__global__ __launch_bounds__(256)
void k_seg(const float* __restrict__ feat, const float* __restrict__ sd,
           const int* __restrict__ lab, float* __restrict__ ws, int n)
{
    __shared__ float s_acc[RREP * RSTRIDE];
    int tid = threadIdx.x;
    for (int i = tid; i < RREP * RSTRIDE; i += 256) s_acc[i] = 0.f;
    __syncthreads();

    int stride = gridDim.x * 256;
    int rep = tid & 7;
    for (int i = blockIdx.x * 256 + tid; i < n; i += stride) {
        int c = lab[i];
        float2 s2 = ((const float2*)sd)[i];
        float v = __expf(s2.y);
        float* base = &s_acc[rep * RSTRIDE + c * CSTRIDE];
        const float4* fp = (const float4*)(feat + (size_t)i * NDIM);
        float4 a = fp[0], b = fp[1], c4 = fp[2], d4 = fp[3];
        atomicAdd(base + 0,  a.x);  atomicAdd(base + 1,  a.y);
        atomicAdd(base + 2,  a.z);  atomicAdd(base + 3,  a.w);
        atomicAdd(base + 4,  b.x);  atomicAdd(base + 5,  b.y);
        atomicAdd(base + 6,  b.z);  atomicAdd(base + 7,  b.w);
        atomicAdd(base + 8,  c4.x); atomicAdd(base + 9,  c4.y);
        atomicAdd(base + 10, c4.z); atomicAdd(base + 11, c4.w);
        atomicAdd(base + 12, d4.x); atomicAdd(base + 13, d4.y);
        atomicAdd(base + 14, d4.z); atomicAdd(base + 15, d4.w);
        atomicAdd(base + 16, 1.0f);
        atomicAdd(base + 17, v);
        atomicAdd(base + 18, v * v);
    }
    __syncthreads();
    for (int idx = tid; idx < NCLU * 19; idx += 256) {
        int c = idx / 19, k = idx % 19;
        float s = 0.f;
        #pragma unroll
        for (int r = 0; r < RREP; ++r) s += s_acc[r * RSTRIDE + c * CSTRIDE + k];
        int dst = (k < 16) ? (F_SF + c * NDIM + k)
                : (k == 16) ? (F_CNT + c)
                : (k == 17) ? (F_SV + c) : (F_SV2 + c);
        unsafeAtomicAdd(&ws[dst], s);
    }
}

__global__ __launch_bounds__(1024)
void k_stats(float* __restrict__ ws)
{
    __shared__ float s_cm[NCLU * NDIM];
    __shared__ float red[1024];
    int tid = threadIdx.x;
    float contrib = 0.f;
    if (tid < NCLU) {
        int c = tid;
        float cnt = ws[F_CNT + c];
        float inv = 1.0f / cnt;
        float var = ws[F_SV + c] * inv;
        float sm  = ws[F_SV2 + c] * inv - var * var;   // mean((v-var)^2)
        float m2 = 0.f;
        for (int d = 0; d < NDIM; ++d) {
            float cm = ws[F_SF + c * NDIM + d] * inv;
            ws[F_CM + c * NDIM + d] = cm;
            s_cm[c * NDIM + d] = cm;
            m2 = fmaf(cm, cm, m2);
        }
        ws[F_M2 + c]  = m2;
        ws[F_I2V + c] = 0.5f / var;
        contrib = W_REG * sqrtf(m2) * (1.0f / NCLU) + W_SMOOTH * sm * (1.0f / NCLU);
    }
    __syncthreads();
    int i = tid >> 5, j = tid & 31;
    if (i != j) {
        float d2 = 0.f;
        for (int d = 0; d < NDIM; ++d) {
            float df = s_cm[i * NDIM + d] - s_cm[j * NDIM + d];
            d2 = fmaf(df, df, d2);
        }
        float dd = sqrtf(d2);
        float h = fmaxf(3.0f - dd, 0.f);   // 2*DELTA_DIST
        contrib += W_DIST * h * h * (1.0f / ((NCLU - 1) * NCLU));
    }
    red[tid] = contrib;
    __syncthreads();
    for (int s = 512; s > 0; s >>= 1) {
        if (tid < s) red[tid] += red[tid + s];
        __syncthreads();
    }
    if (tid == 0) ws[F_SMALL] = red[0];
}

__device__ __forceinline__ void point_body(
    const float* __restrict__ cmg, const float* __restrict__ m2g,
    const float* __restrict__ i2g, const float f[NDIM], float f2,
    int c0, float s0, float& bce, float& sl)
{
    float ownP = 0.f;
    #pragma unroll
    for (int c = 0; c < NCLU; ++c) {
        float dot = 0.f;
        #pragma unroll
        for (int d = 0; d < NDIM; ++d) dot = fmaf(f[d], cmg[c * NDIM + d], dot);
        float D2 = fmaxf(fmaf(-2.0f, dot, f2) + m2g[c], 0.f);
        float q = D2 * i2g[c];            // = -logP  (>= 0)
        float P = __expf(-q);
        // -log1p(-P): series for P<=0.5, exact-ish log for rare large P
        float tE = fmaf(P * P, fmaf(P, fmaf(P, 0.25f, 0.33333333f), 0.5f), P);
        if (P > 0.5f) tE = -__logf(1.0f - P);
        bool own = (c == c0);
        float contrib = own ? q : tE;
        bce += fminf(contrib, 100.f);
        if (own) ownP = P;
    }
    float e = ownP - s0;
    sl = fmaf(e, e, sl);
}

__global__ __launch_bounds__(256)
void k_main(const float* __restrict__ feat, const float* __restrict__ sd,
            const int* __restrict__ lab, const float* __restrict__ ws,
            double* __restrict__ acc, int n)
{
    int tid = threadIdx.x;
    const float* cmg = ws + F_CM;
    const float* m2g = ws + F_M2;
    const float* i2g = ws + F_I2V;

    float bce = 0.f, sl = 0.f;
    int stride = gridDim.x * 512;
    for (int i0 = (blockIdx.x * 256 + tid) * 2; i0 < n; i0 += stride) {
        int i1 = i0 + 1;
        bool has1 = (i1 < n);
        float f0[NDIM], f1[NDIM];
        const float4* fp0 = (const float4*)(feat + (size_t)i0 * NDIM);
        const float4* fp1 = (const float4*)(feat + (size_t)(has1 ? i1 : i0) * NDIM);
        #pragma unroll
        for (int q4 = 0; q4 < 4; ++q4) {
            float4 a = fp0[q4];
            f0[q4*4+0] = a.x; f0[q4*4+1] = a.y; f0[q4*4+2] = a.z; f0[q4*4+3] = a.w;
            float4 b = fp1[q4];
            f1[q4*4+0] = b.x; f1[q4*4+1] = b.y; f1[q4*4+2] = b.z; f1[q4*4+3] = b.w;
        }
        float f20 = 0.f, f21 = 0.f;
        #pragma unroll
        for (int d = 0; d < NDIM; ++d) { f20 = fmaf(f0[d], f0[d], f20); f21 = fmaf(f1[d], f1[d], f21); }
        int c00 = lab[i0];
        int c01 = lab[has1 ? i1 : i0];
        float2 sA = ((const float2*)sd)[i0];
        float2 sB = ((const float2*)sd)[has1 ? i1 : i0];

        point_body(cmg, m2g, i2g, f0, f20, c00, sA.x, bce, sl);
        float bce1 = 0.f, sl1 = 0.f;
        point_body(cmg, m2g, i2g, f1, f21, c01, sB.x, bce1, sl1);
        if (has1) { bce += bce1; sl += sl1; }
    }

    __shared__ float rb[256], rs[256];
    rb[tid] = bce; rs[tid] = sl;
    __syncthreads();
    for (int s = 128; s > 0; s >>= 1) {
        if (tid < s) { rb[tid] += rb[tid + s]; rs[tid] += rs[tid + s]; }
        __syncthreads();
    }
    if (tid == 0) {
        unsafeAtomicAdd(&acc[0], (double)rb[0]);
        unsafeAtomicAdd(&acc[1], (double)rs[0]);
    }
}

__global__ void k_final(const float* __restrict__ ws, const double* __restrict__ acc,
                        float* __restrict__ out, int n)
{
    float var_loss  = (float)(acc[0] / ((double)n * NCLU));
    float seed_loss = (float)(acc[1] / (double)n);
    out[0] = W_VAR * var_loss + ws[F_SMALL] + W_SEED * seed_loss;
}

extern "C" void kernel_launch(void* const* d_in, const int* in_sizes, int n_in,
                              void* d_out, int out_size, void* d_ws, size_t ws_size,
                              hipStream_t stream)
{
    const float* feat = (const float*)d_in[0];
    const float* sd   = (const float*)d_in[1];
    const int*   lab  = (const int*)d_in[2];
    float*  ws  = (float*)d_ws;
    double* acc = (double*)d_ws;
    int n = in_sizes[2];

    hipMemsetAsync(d_ws, 0, F_END * sizeof(float), stream);
    k_seg  <<<1024, 256, 0, stream>>>(feat, sd, lab, ws, n);
    k_stats<<<1, 1024, 0, stream>>>(ws);
    k_main <<<1024, 256, 0, stream>>>(feat, sd, lab, ws, acc, n);
    k_final<<<1, 1, 0, stream>>>(ws, acc, (float*)d_out, n);
}

// Round 3
// 217.179 us; speedup vs baseline: 1.1704x; 1.1704x over previous
//
#include <hip/hip_runtime.h>

#define NCLU 32
#define NDIM 16
#define W_VAR 3.0f
#define W_DIST 1.0f
#define W_REG 0.001f
#define W_SMOOTH 5.0f
#define W_SEED 5.0f

// ws float-index layout ([0,4) = two doubles acc[0]=bce, acc[1]=seed)
enum {
    F_CNT  = 4,            // [4,36)    counts
    F_SV   = 36,           // [36,68)   sum v
    F_SV2  = 68,           // [68,100)  sum v^2
    F_SF   = 100,          // [100,612) sum features [c*16+d]
    F_CM   = 612,          // [612,1124) cluster means
    F_M2   = 1124,         // [1124,1156) |mean|^2
    F_I2V  = 1156,         // [1156,1188) +1/(2 var)
    F_SMALL= 1188,         // dist+reg+smooth (weighted)
    F_END  = 1192
};

#define TILE 256
#define RS 20   // LDS row stride (floats): 16 feat + v + pad; 16B-aligned

__global__ __launch_bounds__(256)
void k_seg(const float* __restrict__ feat, const float* __restrict__ sd,
           const int* __restrict__ lab, float* __restrict__ ws, int n)
{
    __shared__ float sval[TILE * RS];
    __shared__ int   slab[TILE];
    int tid = threadIdx.x;
    int c = tid & 31, g = tid >> 5;

    float acc[19];   // 0..15 feat sums, 16 sum v, 17 sum v^2, 18 count
    #pragma unroll
    for (int k = 0; k < 19; ++k) acc[k] = 0.f;

    int ntile = (n + TILE - 1) / TILE;
    for (int t = blockIdx.x; t < ntile; t += gridDim.x) {
        int pt = t * TILE + tid;
        bool ok = (pt < n);
        size_t p0 = ok ? (size_t)pt : 0;
        const float4* fp = (const float4*)(feat + p0 * NDIM);
        float4 a = fp[0], b = fp[1], c4 = fp[2], d4 = fp[3];
        float v = __expf(sd[2 * p0 + 1]);
        int lp = lab[p0];
        if (!ok) { a.x=a.y=a.z=a.w=b.x=b.y=b.z=b.w=0.f;
                   c4.x=c4.y=c4.z=c4.w=d4.x=d4.y=d4.z=d4.w=0.f; v=0.f; lp=-1; }
        float* row = &sval[tid * RS];
        ((float4*)row)[0] = a; ((float4*)row)[1] = b;
        ((float4*)row)[2] = c4; ((float4*)row)[3] = d4;
        row[16] = v;
        slab[tid] = lp;
        __syncthreads();

        const float* wrow = &sval[(g * 32) * RS];
        const int*   wlab = &slab[g * 32];
        #pragma unroll 8
        for (int p = 0; p < 32; ++p) {
            int l = wlab[p];                       // broadcast (2 addrs/wave)
            float sel = (l == c) ? 1.f : 0.f;
            const float4* vr = (const float4*)&wrow[p * RS];
            float4 x0 = vr[0], x1 = vr[1], x2 = vr[2], x3 = vr[3];
            float vv = wrow[p * RS + 16];
            acc[0]  = fmaf(sel, x0.x, acc[0]);  acc[1]  = fmaf(sel, x0.y, acc[1]);
            acc[2]  = fmaf(sel, x0.z, acc[2]);  acc[3]  = fmaf(sel, x0.w, acc[3]);
            acc[4]  = fmaf(sel, x1.x, acc[4]);  acc[5]  = fmaf(sel, x1.y, acc[5]);
            acc[6]  = fmaf(sel, x1.z, acc[6]);  acc[7]  = fmaf(sel, x1.w, acc[7]);
            acc[8]  = fmaf(sel, x2.x, acc[8]);  acc[9]  = fmaf(sel, x2.y, acc[9]);
            acc[10] = fmaf(sel, x2.z, acc[10]); acc[11] = fmaf(sel, x2.w, acc[11]);
            acc[12] = fmaf(sel, x3.x, acc[12]); acc[13] = fmaf(sel, x3.y, acc[13]);
            acc[14] = fmaf(sel, x3.z, acc[14]); acc[15] = fmaf(sel, x3.w, acc[15]);
            acc[16] = fmaf(sel, vv, acc[16]);
            acc[17] = fmaf(sel, vv * vv, acc[17]);
            acc[18] += sel;
        }
        __syncthreads();
    }

    // block-level cross-g reduce through sval, then global atomics
    #pragma unroll
    for (int k = 0; k < 19; ++k) sval[tid * RS + k] = acc[k];
    __syncthreads();
    for (int idx = tid; idx < NCLU * 19; idx += 256) {
        int cc = idx / 19, k = idx % 19;
        float s = 0.f;
        #pragma unroll
        for (int r = 0; r < 8; ++r) s += sval[(r * 32 + cc) * RS + k];
        int dst = (k < 16) ? (F_SF + cc * NDIM + k)
                : (k == 16) ? (F_SV + cc)
                : (k == 17) ? (F_SV2 + cc) : (F_CNT + cc);
        unsafeAtomicAdd(&ws[dst], s);
    }
}

__global__ __launch_bounds__(1024)
void k_stats(float* __restrict__ ws)
{
    __shared__ float s_cm[NCLU * NDIM];
    __shared__ float red[1024];
    int tid = threadIdx.x;
    float contrib = 0.f;
    if (tid < NCLU) {
        int c = tid;
        float cnt = ws[F_CNT + c];
        float inv = 1.0f / cnt;
        float var = ws[F_SV + c] * inv;
        float sm  = ws[F_SV2 + c] * inv - var * var;
        float m2 = 0.f;
        for (int d = 0; d < NDIM; ++d) {
            float cm = ws[F_SF + c * NDIM + d] * inv;
            ws[F_CM + c * NDIM + d] = cm;
            s_cm[c * NDIM + d] = cm;
            m2 = fmaf(cm, cm, m2);
        }
        ws[F_M2 + c]  = m2;
        ws[F_I2V + c] = 0.5f / var;
        contrib = W_REG * sqrtf(m2) * (1.0f / NCLU) + W_SMOOTH * sm * (1.0f / NCLU);
    }
    __syncthreads();
    int i = tid >> 5, j = tid & 31;
    if (i != j) {
        float d2 = 0.f;
        for (int d = 0; d < NDIM; ++d) {
            float df = s_cm[i * NDIM + d] - s_cm[j * NDIM + d];
            d2 = fmaf(df, df, d2);
        }
        float dd = sqrtf(d2);
        float h = fmaxf(3.0f - dd, 0.f);   // 2*DELTA_DIST
        contrib += W_DIST * h * h * (1.0f / ((NCLU - 1) * NCLU));
    }
    red[tid] = contrib;
    __syncthreads();
    for (int s = 512; s > 0; s >>= 1) {
        if (tid < s) red[tid] += red[tid + s];
        __syncthreads();
    }
    if (tid == 0) ws[F_SMALL] = red[0];
}

__global__ __launch_bounds__(256)
void k_main(const float* __restrict__ feat, const float* __restrict__ sd,
            const int* __restrict__ lab, const float* __restrict__ ws,
            double* __restrict__ acc, int n)
{
    __shared__ float scd[NCLU * RS];  // per cluster: [0..15] cm, [16] m2, [17] 1/(2var)
    int tid = threadIdx.x;
    for (int i = tid; i < NCLU * NDIM; i += 256)
        scd[(i >> 4) * RS + (i & 15)] = ws[F_CM + i];
    if (tid < NCLU) {
        scd[tid * RS + 16] = ws[F_M2 + tid];
        scd[tid * RS + 17] = ws[F_I2V + tid];
    }
    __syncthreads();

    float bce = 0.f, sl = 0.f;
    int stride = gridDim.x * 512;
    for (int i0 = (blockIdx.x * 256 + tid) * 2; i0 < n; i0 += stride) {
        int i1 = i0 + 1;
        bool has1 = (i1 < n);
        size_t j1 = has1 ? (size_t)i1 : (size_t)i0;
        float f0[NDIM], f1[NDIM];
        const float4* fp0 = (const float4*)(feat + (size_t)i0 * NDIM);
        const float4* fp1 = (const float4*)(feat + j1 * NDIM);
        #pragma unroll
        for (int q4 = 0; q4 < 4; ++q4) {
            float4 a = fp0[q4];
            f0[q4*4+0] = a.x; f0[q4*4+1] = a.y; f0[q4*4+2] = a.z; f0[q4*4+3] = a.w;
            float4 b = fp1[q4];
            f1[q4*4+0] = b.x; f1[q4*4+1] = b.y; f1[q4*4+2] = b.z; f1[q4*4+3] = b.w;
        }
        float f20 = 0.f, f21 = 0.f;
        #pragma unroll
        for (int d = 0; d < NDIM; ++d) {
            f20 = fmaf(f0[d], f0[d], f20);
            f21 = fmaf(f1[d], f1[d], f21);
        }
        int c00 = lab[i0];
        int c01 = lab[j1];
        float sA = sd[2 * (size_t)i0];
        float sB = sd[2 * j1];

        float ownP0 = 0.f, ownP1 = 0.f;
        float bce1 = 0.f, sl1 = 0.f;
        #pragma unroll 4
        for (int cc = 0; cc < NCLU; ++cc) {
            const float* cr = &scd[cc * RS];
            const float4* cv = (const float4*)cr;
            float4 m0 = cv[0], m1 = cv[1], m2v = cv[2], m3 = cv[3];
            float mm[NDIM] = { m0.x,m0.y,m0.z,m0.w, m1.x,m1.y,m1.z,m1.w,
                               m2v.x,m2v.y,m2v.z,m2v.w, m3.x,m3.y,m3.z,m3.w };
            float m2c = cr[16], i2c = cr[17];
            float dot0 = 0.f, dot1 = 0.f;
            #pragma unroll
            for (int d = 0; d < NDIM; ++d) {
                dot0 = fmaf(f0[d], mm[d], dot0);
                dot1 = fmaf(f1[d], mm[d], dot1);
            }
            float q0 = fmaxf(fmaf(-2.f, dot0, f20) + m2c, 0.f) * i2c;
            float q1 = fmaxf(fmaf(-2.f, dot1, f21) + m2c, 0.f) * i2c;
            float P0 = __expf(-q0), P1 = __expf(-q1);
            float t0 = fmaf(P0 * P0, fmaf(P0, fmaf(P0, 0.25f, 0.33333333f), 0.5f), P0);
            float t1 = fmaf(P1 * P1, fmaf(P1, fmaf(P1, 0.25f, 0.33333333f), 0.5f), P1);
            if (P0 > 0.5f) t0 = -__logf(1.0f - P0);
            if (P1 > 0.5f) t1 = -__logf(1.0f - P1);
            bool o0 = (cc == c00), o1 = (cc == c01);
            bce  += fminf(o0 ? q0 : t0, 100.f);
            bce1 += fminf(o1 ? q1 : t1, 100.f);
            ownP0 = o0 ? P0 : ownP0;
            ownP1 = o1 ? P1 : ownP1;
        }
        float e0 = ownP0 - sA;
        sl = fmaf(e0, e0, sl);
        if (has1) {
            float e1 = ownP1 - sB;
            bce += bce1;
            sl = fmaf(e1, e1, sl);
        }
    }

    __shared__ float rb[256], rs[256];
    rb[tid] = bce; rs[tid] = sl;
    __syncthreads();
    for (int s = 128; s > 0; s >>= 1) {
        if (tid < s) { rb[tid] += rb[tid + s]; rs[tid] += rs[tid + s]; }
        __syncthreads();
    }
    if (tid == 0) {
        unsafeAtomicAdd(&acc[0], (double)rb[0]);
        unsafeAtomicAdd(&acc[1], (double)rs[0]);
    }
}

__global__ void k_final(const float* __restrict__ ws, const double* __restrict__ acc,
                        float* __restrict__ out, int n)
{
    float var_loss  = (float)(acc[0] / ((double)n * NCLU));
    float seed_loss = (float)(acc[1] / (double)n);
    out[0] = W_VAR * var_loss + ws[F_SMALL] + W_SEED * seed_loss;
}

extern "C" void kernel_launch(void* const* d_in, const int* in_sizes, int n_in,
                              void* d_out, int out_size, void* d_ws, size_t ws_size,
                              hipStream_t stream)
{
    const float* feat = (const float*)d_in[0];
    const float* sd   = (const float*)d_in[1];
    const int*   lab  = (const int*)d_in[2];
    float*  ws  = (float*)d_ws;
    double* acc = (double*)d_ws;
    int n = in_sizes[2];

    hipMemsetAsync(d_ws, 0, F_END * sizeof(float), stream);
    k_seg  <<<1024, 256, 0, stream>>>(feat, sd, lab, ws, n);
    k_stats<<<1, 1024, 0, stream>>>(ws);
    k_main <<<1024, 256, 0, stream>>>(feat, sd, lab, ws, acc, n);
    k_final<<<1, 1, 0, stream>>>(ws, acc, (float*)d_out, n);
}

// Round 4
// 203.972 us; speedup vs baseline: 1.2462x; 1.0648x over previous
//
#include <hip/hip_runtime.h>

#define NCLU 32
#define NDIM 16
#define W_VAR 3.0f
#define W_DIST 1.0f
#define W_REG 0.001f
#define W_SMOOTH 5.0f
#define W_SEED 5.0f

// ws float-index layout ([0,4) = two doubles acc[0]=bce, acc[1]=seed)
enum {
    F_CNT  = 4,            // [4,36)    counts
    F_SV   = 36,           // [36,68)   sum v
    F_SV2  = 68,           // [68,100)  sum v^2
    F_SF   = 100,          // [100,612) sum features [c*16+d]
    F_CM   = 612,          // [612,1124) cluster means
    F_M2   = 1124,         // [1124,1156) |mean|^2
    F_I2V  = 1156,         // [1156,1188) +1/(2 var)
    F_SMALL= 1188,         // dist+reg+smooth (weighted)
    F_END  = 1192
};

typedef __attribute__((ext_vector_type(8)))  short short8v;
typedef __attribute__((ext_vector_type(16))) float f32x16;

__device__ __forceinline__ short f2bf_rz(float x) {
    return (short)(__float_as_uint(x) >> 16);
}
__device__ __forceinline__ short f2bf_rn(float x) {
    unsigned u = __float_as_uint(x);
    u += 0x7FFF + ((u >> 16) & 1);
    return (short)(u >> 16);
}

// ---------------- k_seg: segment sums as MFMA GEMM  S = V^T x Y ----------------
// Per wave: 64 points. LDS: V^T [32 rows][64 pts] bf16 (rows 0-15 feat, 16 v,
// 17 v^2, 18 const 1.0), Y^T [32 clusters][64 pts] one-hot bf16.
// Row-swizzled: element (row, p) at short-index row*64 + (p ^ ((row&15)<<2)).
// 4x mfma_f32_32x32x16_bf16 over the 64 points; D[m=row][n=cluster].
#define NW 4
__global__ __launch_bounds__(256)
void k_seg(const float* __restrict__ feat, const float* __restrict__ sd,
           const int* __restrict__ lab, float* __restrict__ ws, int n)
{
    __shared__ short sm[NW * 4096];   // per wave: [0,2048) V^T, [2048,4096) Y^T
    int tid = threadIdx.x, wid = tid >> 6, lane = tid & 63;
    short* vt = sm + wid * 4096;
    short* yt = vt + 2048;
    int h0 = lane >> 5, m = lane & 31;
    int swz = (m & 15) << 2;
    int rowm = m * 64;

    // constant count-row (row 18 of V^T) = 1.0, written once
    vt[18 * 64 + (lane ^ ((18 & 15) << 2))] = (short)0x3F80;

    f32x16 acc = {};
    int nwin = (n + 63) >> 6;
    int wslot = blockIdx.x * NW + wid, nws = gridDim.x * NW;

    for (int w = wslot; w < nwin; w += nws) {
        int p = w * 64 + lane;
        bool ok = (p < n);
        size_t pc = ok ? (size_t)p : (size_t)(n - 1);
        const float4* fp = (const float4*)(feat + pc * NDIM);
        float4 f0 = fp[0], f1 = fp[1], f2 = fp[2], f3 = fp[3];
        float sy = sd[2 * pc + 1];
        int lb = lab[pc];
        float v = __expf(sy);

        // zero Y^T (2048 shorts = 256 int4; 64 lanes x 4)
        int4 z = {0, 0, 0, 0};
        int4* yz = (int4*)yt;
        yz[lane] = z; yz[lane + 64] = z; yz[lane + 128] = z; yz[lane + 192] = z;
        // one-hot scatter
        if (ok) yt[lb * 64 + (lane ^ ((lb & 15) << 2))] = (short)0x3F80;

        // V^T column write (18 b16 scatters, conflict-free per row)
        float ff[16] = { f0.x,f0.y,f0.z,f0.w, f1.x,f1.y,f1.z,f1.w,
                         f2.x,f2.y,f2.z,f2.w, f3.x,f3.y,f3.z,f3.w };
        #pragma unroll
        for (int j = 0; j < 16; ++j)
            vt[j * 64 + (lane ^ (j << 2))] = f2bf_rz(ff[j]);
        vt[16 * 64 + (lane ^ ((16 & 15) << 2))] = f2bf_rn(v);
        vt[17 * 64 + (lane ^ ((17 & 15) << 2))] = f2bf_rn(v * v);

        // 4 MFMAs, K=16 points each; A/B frag: k = 4*h0 + jj + 8*h (+16q)
        #pragma unroll
        for (int q = 0; q < 4; ++q) {
            int o0 = rowm + ((4 * h0 + 16 * q) ^ swz);
            int o1 = rowm + ((4 * h0 + 8 + 16 * q) ^ swz);
            short4 a0 = *(short4*)(vt + o0), a1 = *(short4*)(vt + o1);
            short4 b0 = *(short4*)(yt + o0), b1 = *(short4*)(yt + o1);
            short8v A = { a0.x, a0.y, a0.z, a0.w, a1.x, a1.y, a1.z, a1.w };
            short8v B = { b0.x, b0.y, b0.z, b0.w, b1.x, b1.y, b1.z, b1.w };
            acc = __builtin_amdgcn_mfma_f32_32x32x16_bf16(A, B, acc, 0, 0, 0);
        }
    }

    // in-block reduce of D fragments (4 waves) then 608 global atomics
    __syncthreads();
    float* fsm = (float*)sm;   // [wid][lane][16]
    #pragma unroll
    for (int r = 0; r < 16; ++r) fsm[wid * 1024 + lane * 16 + r] = acc[r];
    __syncthreads();
    for (int o = tid; o < NCLU * 19; o += 256) {
        int c = o / 19, j = o % 19;
        int hh = (j >> 2) & 1, r = (j & 3) + 4 * (j >> 3);
        int ln = c + 32 * hh;
        float s = 0.f;
        #pragma unroll
        for (int ww = 0; ww < NW; ++ww) s += fsm[ww * 1024 + ln * 16 + r];
        int dst = (j < 16) ? (F_SF + c * NDIM + j)
                : (j == 16) ? (F_SV + c)
                : (j == 17) ? (F_SV2 + c) : (F_CNT + c);
        unsafeAtomicAdd(&ws[dst], s);
    }
}

__global__ __launch_bounds__(1024)
void k_stats(float* __restrict__ ws)
{
    __shared__ float s_cm[NCLU * NDIM];
    __shared__ float red[1024];
    int tid = threadIdx.x;
    float contrib = 0.f;
    if (tid < NCLU) {
        int c = tid;
        float cnt = ws[F_CNT + c];
        float inv = 1.0f / cnt;
        float var = ws[F_SV + c] * inv;
        float sm  = ws[F_SV2 + c] * inv - var * var;
        float m2 = 0.f;
        for (int d = 0; d < NDIM; ++d) {
            float cm = ws[F_SF + c * NDIM + d] * inv;
            ws[F_CM + c * NDIM + d] = cm;
            s_cm[c * NDIM + d] = cm;
            m2 = fmaf(cm, cm, m2);
        }
        ws[F_M2 + c]  = m2;
        ws[F_I2V + c] = 0.5f / var;
        contrib = W_REG * sqrtf(m2) * (1.0f / NCLU) + W_SMOOTH * sm * (1.0f / NCLU);
    }
    __syncthreads();
    int i = tid >> 5, j = tid & 31;
    if (i != j) {
        float d2 = 0.f;
        for (int d = 0; d < NDIM; ++d) {
            float df = s_cm[i * NDIM + d] - s_cm[j * NDIM + d];
            d2 = fmaf(df, df, d2);
        }
        float dd = sqrtf(d2);
        float h = fmaxf(3.0f - dd, 0.f);   // 2*DELTA_DIST
        contrib += W_DIST * h * h * (1.0f / ((NCLU - 1) * NCLU));
    }
    red[tid] = contrib;
    __syncthreads();
    for (int s = 512; s > 0; s >>= 1) {
        if (tid < s) red[tid] += red[tid + s];
        __syncthreads();
    }
    if (tid == 0) ws[F_SMALL] = red[0];
}

#define RS 20
__global__ __launch_bounds__(256)
void k_main(const float* __restrict__ feat, const float* __restrict__ sd,
            const int* __restrict__ lab, const float* __restrict__ ws,
            double* __restrict__ acc, int n)
{
    __shared__ float scd[NCLU * RS];  // per cluster: [0..15] cm, [16] m2, [17] 1/(2var)
    int tid = threadIdx.x;
    for (int i = tid; i < NCLU * NDIM; i += 256)
        scd[(i >> 4) * RS + (i & 15)] = ws[F_CM + i];
    if (tid < NCLU) {
        scd[tid * RS + 16] = ws[F_M2 + tid];
        scd[tid * RS + 17] = ws[F_I2V + tid];
    }
    __syncthreads();

    float bce = 0.f, sl = 0.f;
    int stride = gridDim.x * 512;
    for (int i0 = (blockIdx.x * 256 + tid) * 2; i0 < n; i0 += stride) {
        int i1 = i0 + 1;
        bool has1 = (i1 < n);
        size_t j1 = has1 ? (size_t)i1 : (size_t)i0;
        float f0[NDIM], f1[NDIM];
        const float4* fp0 = (const float4*)(feat + (size_t)i0 * NDIM);
        const float4* fp1 = (const float4*)(feat + j1 * NDIM);
        #pragma unroll
        for (int q4 = 0; q4 < 4; ++q4) {
            float4 a = fp0[q4];
            f0[q4*4+0] = a.x; f0[q4*4+1] = a.y; f0[q4*4+2] = a.z; f0[q4*4+3] = a.w;
            float4 b = fp1[q4];
            f1[q4*4+0] = b.x; f1[q4*4+1] = b.y; f1[q4*4+2] = b.z; f1[q4*4+3] = b.w;
        }
        float f20 = 0.f, f21 = 0.f;
        #pragma unroll
        for (int d = 0; d < NDIM; ++d) {
            f20 = fmaf(f0[d], f0[d], f20);
            f21 = fmaf(f1[d], f1[d], f21);
        }
        int c00 = lab[i0];
        int c01 = lab[j1];
        float sA = sd[2 * (size_t)i0];
        float sB = sd[2 * j1];

        float ownP0 = 0.f, ownP1 = 0.f;
        float bce1 = 0.f;
        #pragma unroll 4
        for (int cc = 0; cc < NCLU; ++cc) {
            const float* cr = &scd[cc * RS];
            const float4* cv = (const float4*)cr;
            float4 m0 = cv[0], m1 = cv[1], m2v = cv[2], m3 = cv[3];
            float mm[NDIM] = { m0.x,m0.y,m0.z,m0.w, m1.x,m1.y,m1.z,m1.w,
                               m2v.x,m2v.y,m2v.z,m2v.w, m3.x,m3.y,m3.z,m3.w };
            float m2c = cr[16], i2c = cr[17];
            float dot0 = 0.f, dot1 = 0.f;
            #pragma unroll
            for (int d = 0; d < NDIM; ++d) {
                dot0 = fmaf(f0[d], mm[d], dot0);
                dot1 = fmaf(f1[d], mm[d], dot1);
            }
            float q0 = fmaxf(fmaf(-2.f, dot0, f20) + m2c, 0.f) * i2c;
            float q1 = fmaxf(fmaf(-2.f, dot1, f21) + m2c, 0.f) * i2c;
            float P0 = __expf(-q0), P1 = __expf(-q1);
            float t0 = fmaf(P0 * P0, fmaf(P0, fmaf(P0, 0.25f, 0.33333333f), 0.5f), P0);
            float t1 = fmaf(P1 * P1, fmaf(P1, fmaf(P1, 0.25f, 0.33333333f), 0.5f), P1);
            if (P0 > 0.5f) t0 = -__logf(1.0f - P0);
            if (P1 > 0.5f) t1 = -__logf(1.0f - P1);
            bool o0 = (cc == c00), o1 = (cc == c01);
            bce  += fminf(o0 ? q0 : t0, 100.f);
            bce1 += fminf(o1 ? q1 : t1, 100.f);
            ownP0 = o0 ? P0 : ownP0;
            ownP1 = o1 ? P1 : ownP1;
        }
        float e0 = ownP0 - sA;
        sl = fmaf(e0, e0, sl);
        if (has1) {
            float e1 = ownP1 - sB;
            bce += bce1;
            sl = fmaf(e1, e1, sl);
        }
    }

    __shared__ float rb[256], rsd[256];
    rb[tid] = bce; rsd[tid] = sl;
    __syncthreads();
    for (int s = 128; s > 0; s >>= 1) {
        if (tid < s) { rb[tid] += rb[tid + s]; rsd[tid] += rsd[tid + s]; }
        __syncthreads();
    }
    if (tid == 0) {
        unsafeAtomicAdd(&acc[0], (double)rb[0]);
        unsafeAtomicAdd(&acc[1], (double)rsd[0]);
    }
}

__global__ void k_final(const float* __restrict__ ws, const double* __restrict__ acc,
                        float* __restrict__ out, int n)
{
    float var_loss  = (float)(acc[0] / ((double)n * NCLU));
    float seed_loss = (float)(acc[1] / (double)n);
    out[0] = W_VAR * var_loss + ws[F_SMALL] + W_SEED * seed_loss;
}

extern "C" void kernel_launch(void* const* d_in, const int* in_sizes, int n_in,
                              void* d_out, int out_size, void* d_ws, size_t ws_size,
                              hipStream_t stream)
{
    const float* feat = (const float*)d_in[0];
    const float* sd   = (const float*)d_in[1];
    const int*   lab  = (const int*)d_in[2];
    float*  ws  = (float*)d_ws;
    double* acc = (double*)d_ws;
    int n = in_sizes[2];

    hipMemsetAsync(d_ws, 0, F_END * sizeof(float), stream);
    k_seg  <<<1024, 256, 0, stream>>>(feat, sd, lab, ws, n);
    k_stats<<<1, 1024, 0, stream>>>(ws);
    k_main <<<1024, 256, 0, stream>>>(feat, sd, lab, ws, acc, n);
    k_final<<<1, 1, 0, stream>>>(ws, acc, (float*)d_out, n);
}

// Round 5
// 92.198 us; speedup vs baseline: 2.7569x; 2.2123x over previous
//
#include <hip/hip_runtime.h>

#define NCLU 32
#define NDIM 16
#define W_VAR 3.0f
#define W_DIST 1.0f
#define W_REG 0.001f
#define W_SMOOTH 5.0f
#define W_SEED 5.0f

#define NBS 512                 // k_seg blocks
#define NBM 512                 // k_main blocks
#define SEG_STRIDE 640          // floats per k_seg block partial slice (608 used)
// ws float-index layout:
//   [0, NBS*640)          per-block k_seg partials
//   PST..                 cluster stats
#define PST     (NBS * SEG_STRIDE)
#define G_CM    (PST)           // 512 floats
#define G_M2    (PST + 512)     // 32
#define G_IV    (PST + 544)     // 32: +1/(2var)
#define G_SMALL (PST + 576)     // 1
#define PMAIN   (PST + 640)     // float2[NBM] main partials

typedef __attribute__((ext_vector_type(8)))  short short8v;
typedef __attribute__((ext_vector_type(16))) float f32x16;

__device__ __forceinline__ short f2bf_rz(float x) {
    return (short)(__float_as_uint(x) >> 16);
}
__device__ __forceinline__ short f2bf_rn(float x) {
    unsigned u = __float_as_uint(x);
    u += 0x7FFF + ((u >> 16) & 1);
    return (short)(u >> 16);
}

// ---------------- k_seg: segment sums as MFMA GEMM  S = V^T x Y ----------------
// Per wave: 64-point windows. LDS per wave: V^T [32 rows][64 cols] bf16
// (rows 0-15 feat, 16 v, 17 v^2, 18 const 1), Y^T [32 rows][64 cols] one-hot.
// Column storage permuted (bit2<->bit3 of low nibble) so each MFMA A/B fragment
// is ONE contiguous ds_read_b128 in register order. Row-XOR swizzle (bits>=3)
// for bank spread. 4x mfma_f32_32x32x16_bf16 per window.
#define NW 4
__global__ __launch_bounds__(256)
void k_seg(const float* __restrict__ feat, const float* __restrict__ sd,
           const int* __restrict__ lab, float* __restrict__ ws, int n)
{
    __shared__ short sm[NW * 4096];   // per wave: [0,2048) V^T, [2048,4096) Y^T
    int tid = threadIdx.x, wid = tid >> 6, lane = tid & 63;
    short* vt = sm + wid * 4096;
    short* yt = vt + 2048;
    int h0 = lane >> 5, m = lane & 31;
    int rowm = m * 64;
    // permuted column for this lane's point: swap bit2<->bit3 of low nibble
    int csig = (lane & 0x33) | ((lane & 4) << 1) | ((lane & 8) >> 1);

    // zero Y^T once (private per wave), const count-row of V^T
    {
        int4 z = {0, 0, 0, 0};
        int4* yz = (int4*)yt;
        yz[lane] = z; yz[lane + 64] = z; yz[lane + 128] = z; yz[lane + 192] = z;
        vt[18 * 64 + (csig ^ ((18 & 7) << 3))] = (short)0x3F80;
    }

    f32x16 acc = {};
    int nwin = (n + 63) >> 6;
    int wslot = blockIdx.x * NW + wid, nws = gridDim.x * NW;
    int prev = -1;

    for (int w = wslot; w < nwin; w += nws) {
        int p = w * 64 + lane;
        bool ok = (p < n);
        size_t pc = ok ? (size_t)p : (size_t)(n - 1);
        const float4* fp = (const float4*)(feat + pc * NDIM);
        float4 f0 = fp[0], f1 = fp[1], f2 = fp[2], f3 = fp[3];
        float sy = sd[2 * pc + 1];
        int lb = lab[pc];
        float v = __expf(sy);

        // one-hot maintenance: clear old, set new
        if (prev >= 0) yt[prev * 64 + (csig ^ ((prev & 7) << 3))] = 0;
        if (ok)        yt[lb * 64 + (csig ^ ((lb & 7) << 3))] = (short)0x3F80;
        prev = ok ? lb : -1;

        // V^T column write (18 b16 scatters; stale cols harmless: Y col is 0)
        float ff[16] = { f0.x,f0.y,f0.z,f0.w, f1.x,f1.y,f1.z,f1.w,
                         f2.x,f2.y,f2.z,f2.w, f3.x,f3.y,f3.z,f3.w };
        #pragma unroll
        for (int j = 0; j < 16; ++j)
            vt[j * 64 + (csig ^ ((j & 7) << 3))] = f2bf_rz(ff[j]);
        vt[16 * 64 + (csig ^ ((16 & 7) << 3))] = f2bf_rn(v);
        vt[17 * 64 + (csig ^ ((17 & 7) << 3))] = f2bf_rn(v * v);

        // 4 MFMAs; fragment = one b128 at permuted offset
        #pragma unroll
        for (int q = 0; q < 4; ++q) {
            int o = rowm + ((8 * h0 + 16 * q) ^ ((m & 7) << 3));
            short8v A = *(short8v*)(vt + o);
            short8v B = *(short8v*)(yt + o);
            acc = __builtin_amdgcn_mfma_f32_32x32x16_bf16(A, B, acc, 0, 0, 0);
        }
    }

    // in-block reduce of D fragments, then PRIVATE coalesced stores (no atomics)
    __syncthreads();
    float* fsm = (float*)sm;   // [wid][lane][16]
    #pragma unroll
    for (int r = 0; r < 16; ++r) fsm[wid * 1024 + lane * 16 + r] = acc[r];
    __syncthreads();
    for (int o = tid; o < NCLU * 19; o += 256) {
        int c = o / 19, j = o % 19;
        int hh = (j >> 2) & 1, r = (j & 3) + 4 * (j >> 3);
        int ln = c + 32 * hh;
        float s = 0.f;
        #pragma unroll
        for (int ww = 0; ww < NW; ++ww) s += fsm[ww * 1024 + ln * 16 + r];
        ws[(size_t)blockIdx.x * SEG_STRIDE + o] = s;
    }
}

// ---------------- k_redstats: deterministic partial reduce + cluster stats ----
__global__ __launch_bounds__(1024)
void k_redstats(float* __restrict__ ws)
{
    __shared__ float sums[NCLU * 19];
    __shared__ float s_cm[NCLU * NDIM];
    __shared__ float red[1024];
    int tid = threadIdx.x;

    if (tid < NCLU * 19) {
        float s = 0.f;
        #pragma unroll 8
        for (int b = 0; b < NBS; ++b) s += ws[(size_t)b * SEG_STRIDE + tid];
        sums[tid] = s;
    }
    __syncthreads();

    float contrib = 0.f;
    if (tid < NCLU) {
        int c = tid;
        float cnt = sums[c * 19 + 18];
        float inv = 1.0f / cnt;
        float var = sums[c * 19 + 16] * inv;
        float smo = sums[c * 19 + 17] * inv - var * var;   // mean((v-var)^2)
        float m2 = 0.f;
        for (int d = 0; d < NDIM; ++d) {
            float cm = sums[c * 19 + d] * inv;
            ws[G_CM + c * NDIM + d] = cm;
            s_cm[c * NDIM + d] = cm;
            m2 = fmaf(cm, cm, m2);
        }
        ws[G_M2 + c] = m2;
        ws[G_IV + c] = 0.5f / var;
        contrib = W_REG * sqrtf(m2) * (1.0f / NCLU) + W_SMOOTH * smo * (1.0f / NCLU);
    }
    __syncthreads();
    int i = tid >> 5, j = tid & 31;
    if (i != j) {
        float d2 = 0.f;
        for (int d = 0; d < NDIM; ++d) {
            float df = s_cm[i * NDIM + d] - s_cm[j * NDIM + d];
            d2 = fmaf(df, df, d2);
        }
        float dd = sqrtf(d2);
        float h = fmaxf(3.0f - dd, 0.f);   // 2*DELTA_DIST
        contrib += W_DIST * h * h * (1.0f / ((NCLU - 1) * NCLU));
    }
    red[tid] = contrib;
    __syncthreads();
    for (int s = 512; s > 0; s >>= 1) {
        if (tid < s) red[tid] += red[tid + s];
        __syncthreads();
    }
    if (tid == 0) ws[G_SMALL] = red[0];
}

// ---------------- k_main: BCE + seed loss ----------------
#define RS 20
__global__ __launch_bounds__(256)
void k_main(const float* __restrict__ feat, const float* __restrict__ sd,
            const int* __restrict__ lab, float* __restrict__ ws, int n)
{
    __shared__ float scd[NCLU * RS];  // per cluster: [0..15] cm, [16] m2, [17] 1/(2var)
    int tid = threadIdx.x;
    for (int i = tid; i < NCLU * NDIM; i += 256)
        scd[(i >> 4) * RS + (i & 15)] = ws[G_CM + i];
    if (tid < NCLU) {
        scd[tid * RS + 16] = ws[G_M2 + tid];
        scd[tid * RS + 17] = ws[G_IV + tid];
    }
    __syncthreads();

    float bce = 0.f, sl = 0.f;
    int stride = gridDim.x * 512;
    for (int i0 = (blockIdx.x * 256 + tid) * 2; i0 < n; i0 += stride) {
        int i1 = i0 + 1;
        bool has1 = (i1 < n);
        size_t j1 = has1 ? (size_t)i1 : (size_t)i0;
        float f0[NDIM], f1[NDIM];
        const float4* fp0 = (const float4*)(feat + (size_t)i0 * NDIM);
        const float4* fp1 = (const float4*)(feat + j1 * NDIM);
        #pragma unroll
        for (int q4 = 0; q4 < 4; ++q4) {
            float4 a = fp0[q4];
            f0[q4*4+0] = a.x; f0[q4*4+1] = a.y; f0[q4*4+2] = a.z; f0[q4*4+3] = a.w;
            float4 b = fp1[q4];
            f1[q4*4+0] = b.x; f1[q4*4+1] = b.y; f1[q4*4+2] = b.z; f1[q4*4+3] = b.w;
        }
        float f20 = 0.f, f21 = 0.f;
        #pragma unroll
        for (int d = 0; d < NDIM; ++d) {
            f20 = fmaf(f0[d], f0[d], f20);
            f21 = fmaf(f1[d], f1[d], f21);
        }
        int c00 = lab[i0];
        int c01 = lab[j1];
        float sA = sd[2 * (size_t)i0];
        float sB = sd[2 * j1];

        float ownP0 = 0.f, ownP1 = 0.f;
        float bce1 = 0.f;
        #pragma unroll 4
        for (int cc = 0; cc < NCLU; ++cc) {
            const float* cr = &scd[cc * RS];
            const float4* cv = (const float4*)cr;
            float4 m0 = cv[0], m1 = cv[1], m2v = cv[2], m3 = cv[3];
            float mm[NDIM] = { m0.x,m0.y,m0.z,m0.w, m1.x,m1.y,m1.z,m1.w,
                               m2v.x,m2v.y,m2v.z,m2v.w, m3.x,m3.y,m3.z,m3.w };
            float m2c = cr[16], i2c = cr[17];
            float dot0 = 0.f, dot1 = 0.f;
            #pragma unroll
            for (int d = 0; d < NDIM; ++d) {
                dot0 = fmaf(f0[d], mm[d], dot0);
                dot1 = fmaf(f1[d], mm[d], dot1);
            }
            float q0 = fmaxf(fmaf(-2.f, dot0, f20) + m2c, 0.f) * i2c;
            float q1 = fmaxf(fmaf(-2.f, dot1, f21) + m2c, 0.f) * i2c;
            float P0 = __expf(-q0), P1 = __expf(-q1);
            float t0 = fmaf(P0 * P0, fmaf(P0, fmaf(P0, 0.25f, 0.33333333f), 0.5f), P0);
            float t1 = fmaf(P1 * P1, fmaf(P1, fmaf(P1, 0.25f, 0.33333333f), 0.5f), P1);
            if (P0 > 0.5f) t0 = -__logf(1.0f - P0);
            if (P1 > 0.5f) t1 = -__logf(1.0f - P1);
            bool o0 = (cc == c00), o1 = (cc == c01);
            bce  += fminf(o0 ? q0 : t0, 100.f);
            bce1 += fminf(o1 ? q1 : t1, 100.f);
            ownP0 = o0 ? P0 : ownP0;
            ownP1 = o1 ? P1 : ownP1;
        }
        float e0 = ownP0 - sA;
        sl = fmaf(e0, e0, sl);
        if (has1) {
            float e1 = ownP1 - sB;
            bce += bce1;
            sl = fmaf(e1, e1, sl);
        }
    }

    __shared__ float rb[256], rsd[256];
    rb[tid] = bce; rsd[tid] = sl;
    __syncthreads();
    for (int s = 128; s > 0; s >>= 1) {
        if (tid < s) { rb[tid] += rb[tid + s]; rsd[tid] += rsd[tid + s]; }
        __syncthreads();
    }
    if (tid == 0) {
        float2 pr; pr.x = rb[0]; pr.y = rsd[0];
        ((float2*)(ws + PMAIN))[blockIdx.x] = pr;   // private slot, no atomics
    }
}

__global__ __launch_bounds__(512)
void k_final(const float* __restrict__ ws, float* __restrict__ out, int n)
{
    __shared__ float rb[512], rs[512];
    int tid = threadIdx.x;
    float2 p = ((const float2*)(ws + PMAIN))[tid];
    rb[tid] = p.x; rs[tid] = p.y;
    __syncthreads();
    for (int s = 256; s > 0; s >>= 1) {
        if (tid < s) { rb[tid] += rb[tid + s]; rs[tid] += rs[tid + s]; }
        __syncthreads();
    }
    if (tid == 0) {
        float var_loss  = rb[0] / ((float)n * (float)NCLU);
        float seed_loss = rs[0] / (float)n;
        out[0] = W_VAR * var_loss + ws[G_SMALL] + W_SEED * seed_loss;
    }
}

extern "C" void kernel_launch(void* const* d_in, const int* in_sizes, int n_in,
                              void* d_out, int out_size, void* d_ws, size_t ws_size,
                              hipStream_t stream)
{
    const float* feat = (const float*)d_in[0];
    const float* sd   = (const float*)d_in[1];
    const int*   lab  = (const int*)d_in[2];
    float* ws = (float*)d_ws;
    int n = in_sizes[2];

    k_seg     <<<NBS, 256,  0, stream>>>(feat, sd, lab, ws, n);
    k_redstats<<<1,   1024, 0, stream>>>(ws);
    k_main    <<<NBM, 256,  0, stream>>>(feat, sd, lab, ws, n);
    k_final   <<<1,   512,  0, stream>>>(ws, (float*)d_out, n);
}

// Round 6
// 59.854 us; speedup vs baseline: 4.2467x; 1.5404x over previous
//
#include <hip/hip_runtime.h>

#define NCLU 32
#define NDIM 16
#define W_VAR 3.0f
#define W_DIST 1.0f
#define W_REG 0.001f
#define W_SMOOTH 5.0f
#define W_SEED 5.0f

#define NBS 512                 // k_seg blocks
#define NBM 1024                // k_main blocks
#define SEG_STRIDE 640          // floats per k_seg block partial slice (608 used)
// ws float-index layout:
#define PST     (NBS * SEG_STRIDE)
#define G_CM    (PST)           // 512 floats: cluster means
#define G_M2    (PST + 512)     // 32: |mean|^2
#define G_IV    (PST + 544)     // 32: +1/(2 var)
#define G_SMALL (PST + 576)     // 1: dist+reg+smooth (weighted)
#define G_SUMS  (PST + 608)     // 608: reduced segment sums
#define PMAIN   (PST + 1280)    // float2[NBM] main partials

typedef __attribute__((ext_vector_type(8)))  short short8v;
typedef __attribute__((ext_vector_type(16))) float f32x16;

__device__ __forceinline__ short f2bf_rz(float x) {
    return (short)(__float_as_uint(x) >> 16);
}
__device__ __forceinline__ short f2bf_rn(float x) {
    unsigned u = __float_as_uint(x);
    u += 0x7FFF + ((u >> 16) & 1);
    return (short)(u >> 16);
}

// ---------------- k_seg: segment sums as MFMA GEMM  S = V^T x Y ----------------
#define NW 4
__global__ __launch_bounds__(256)
void k_seg(const float* __restrict__ feat, const float* __restrict__ sd,
           const int* __restrict__ lab, float* __restrict__ ws, int n)
{
    __shared__ short sm[NW * 4096];   // per wave: [0,2048) V^T, [2048,4096) Y^T
    int tid = threadIdx.x, wid = tid >> 6, lane = tid & 63;
    short* vt = sm + wid * 4096;
    short* yt = vt + 2048;
    int h0 = lane >> 5, m = lane & 31;
    int rowm = m * 64;
    // permuted column for this lane's point: swap bit2<->bit3 of low nibble
    int csig = (lane & 0x33) | ((lane & 4) << 1) | ((lane & 8) >> 1);

    {
        int4 z = {0, 0, 0, 0};
        int4* yz = (int4*)yt;
        yz[lane] = z; yz[lane + 64] = z; yz[lane + 128] = z; yz[lane + 192] = z;
        vt[18 * 64 + (csig ^ ((18 & 7) << 3))] = (short)0x3F80;
    }

    f32x16 acc = {};
    int nwin = (n + 63) >> 6;
    int wslot = blockIdx.x * NW + wid, nws = gridDim.x * NW;
    int prev = -1;

    for (int w = wslot; w < nwin; w += nws) {
        int p = w * 64 + lane;
        bool ok = (p < n);
        size_t pc = ok ? (size_t)p : (size_t)(n - 1);
        const float4* fp = (const float4*)(feat + pc * NDIM);
        float4 f0 = fp[0], f1 = fp[1], f2 = fp[2], f3 = fp[3];
        float sy = sd[2 * pc + 1];
        int lb = lab[pc];
        float v = __expf(sy);

        if (prev >= 0) yt[prev * 64 + (csig ^ ((prev & 7) << 3))] = 0;
        if (ok)        yt[lb * 64 + (csig ^ ((lb & 7) << 3))] = (short)0x3F80;
        prev = ok ? lb : -1;

        float ff[16] = { f0.x,f0.y,f0.z,f0.w, f1.x,f1.y,f1.z,f1.w,
                         f2.x,f2.y,f2.z,f2.w, f3.x,f3.y,f3.z,f3.w };
        #pragma unroll
        for (int j = 0; j < 16; ++j)
            vt[j * 64 + (csig ^ ((j & 7) << 3))] = f2bf_rz(ff[j]);
        vt[16 * 64 + (csig ^ ((16 & 7) << 3))] = f2bf_rn(v);
        vt[17 * 64 + (csig ^ ((17 & 7) << 3))] = f2bf_rn(v * v);

        #pragma unroll
        for (int q = 0; q < 4; ++q) {
            int o = rowm + ((8 * h0 + 16 * q) ^ ((m & 7) << 3));
            short8v A = *(short8v*)(vt + o);
            short8v B = *(short8v*)(yt + o);
            acc = __builtin_amdgcn_mfma_f32_32x32x16_bf16(A, B, acc, 0, 0, 0);
        }
    }

    __syncthreads();
    float* fsm = (float*)sm;   // [wid][lane][16]
    #pragma unroll
    for (int r = 0; r < 16; ++r) fsm[wid * 1024 + lane * 16 + r] = acc[r];
    __syncthreads();
    for (int o = tid; o < NCLU * 19; o += 256) {
        int c = o / 19, j = o % 19;
        int hh = (j >> 2) & 1, r = (j & 3) + 4 * (j >> 3);
        int ln = c + 32 * hh;
        float s = 0.f;
        #pragma unroll
        for (int ww = 0; ww < NW; ++ww) s += fsm[ww * 1024 + ln * 16 + r];
        ws[(size_t)blockIdx.x * SEG_STRIDE + o] = s;
    }
}

// ---------------- k_red1: parallel reduce of per-block partials ----------------
__global__ __launch_bounds__(256)
void k_red1(float* __restrict__ ws)
{
    __shared__ float red[256];
    int tid = threadIdx.x;
    int o = blockIdx.x * 4 + (tid & 3);    // 152 blocks x 4 outputs = 608
    int brow = tid >> 2;                   // 64 rows
    float s = 0.f;
    #pragma unroll
    for (int k = 0; k < 8; ++k)
        s += ws[(size_t)(brow + 64 * k) * SEG_STRIDE + o];
    red[tid] = s;
    __syncthreads();
    for (int st = 128; st >= 4; st >>= 1) {
        if (tid < st) red[tid] += red[tid + st];
        __syncthreads();
    }
    if (tid < 4) ws[G_SUMS + blockIdx.x * 4 + tid] = red[tid];
}

// ---------------- k_stats: cluster stats + small losses ----------------
__global__ __launch_bounds__(1024)
void k_stats(float* __restrict__ ws)
{
    __shared__ float sums[NCLU * 19];
    __shared__ float s_cm[NCLU * NDIM];
    __shared__ float red[1024];
    int tid = threadIdx.x;
    if (tid < NCLU * 19) sums[tid] = ws[G_SUMS + tid];
    __syncthreads();

    float contrib = 0.f;
    if (tid < NCLU) {
        int c = tid;
        float cnt = sums[c * 19 + 18];
        float inv = 1.0f / cnt;
        float var = sums[c * 19 + 16] * inv;
        float smo = sums[c * 19 + 17] * inv - var * var;   // mean((v-var)^2)
        float m2 = 0.f;
        for (int d = 0; d < NDIM; ++d) {
            float cm = sums[c * 19 + d] * inv;
            ws[G_CM + c * NDIM + d] = cm;
            s_cm[c * NDIM + d] = cm;
            m2 = fmaf(cm, cm, m2);
        }
        ws[G_M2 + c] = m2;
        ws[G_IV + c] = 0.5f / var;
        contrib = W_REG * sqrtf(m2) * (1.0f / NCLU) + W_SMOOTH * smo * (1.0f / NCLU);
    }
    __syncthreads();
    int i = tid >> 5, j = tid & 31;
    if (i != j) {
        float d2 = 0.f;
        for (int d = 0; d < NDIM; ++d) {
            float df = s_cm[i * NDIM + d] - s_cm[j * NDIM + d];
            d2 = fmaf(df, df, d2);
        }
        float dd = sqrtf(d2);
        float h = fmaxf(3.0f - dd, 0.f);   // 2*DELTA_DIST
        contrib += W_DIST * h * h * (1.0f / ((NCLU - 1) * NCLU));
    }
    red[tid] = contrib;
    __syncthreads();
    for (int s = 512; s > 0; s >>= 1) {
        if (tid < s) red[tid] += red[tid + s];
        __syncthreads();
    }
    if (tid == 0) ws[G_SMALL] = red[0];
}

// ---------------- k_main: BCE + seed via MFMA  D = cmeans x feat^T -------------
// Per wave, tile of 32 points. A (const) = cmeans[32 clu][16 dims] bf16,
// B = feat^T slice for 32 points. D[m=cluster][n=point]: lane l owns point
// pb+(l&31) and clusters {(r&3)+8*(r>>2)+4*(l>>5)}. All per-point data
// (f2, label, s0) is lane-local; no LDS in the hot loop.
__global__ __launch_bounds__(256)
void k_main(const float* __restrict__ feat, const float* __restrict__ sd,
            const int* __restrict__ lab, float* __restrict__ ws, int n)
{
    int tid = threadIdx.x, wid = tid >> 6, lane = tid & 63;
    int h0 = lane >> 5, pl = lane & 31;

    // A-fragment: cmeans row m=pl, dims {4h0..4h0+3, 4h0+8..4h0+11}
    const float* cmrow = ws + G_CM + pl * NDIM + 4 * h0;
    float4 ca = *(const float4*)cmrow;
    float4 cb = *(const float4*)(cmrow + 8);
    short8v A = { f2bf_rn(ca.x), f2bf_rn(ca.y), f2bf_rn(ca.z), f2bf_rn(ca.w),
                  f2bf_rn(cb.x), f2bf_rn(cb.y), f2bf_rn(cb.z), f2bf_rn(cb.w) };

    // per-r cluster constants (static-indexed registers)
    float ar[16], ivr[16], c2r[16];
    #pragma unroll
    for (int r = 0; r < 16; ++r) {
        int c = (r & 3) + 8 * (r >> 2) + 4 * h0;
        float m2 = ws[G_M2 + c];
        float iv = ws[G_IV + c];
        ar[r] = m2 * iv; ivr[r] = iv; c2r[r] = 2.0f * iv;
    }

    float bce = 0.f, sl = 0.f;
    int nt = (n + 31) >> 5;
    int slot = blockIdx.x * 4 + wid, nslots = gridDim.x * 4;

    for (int t = slot; t < nt; t += nslots) {
        int p = t * 32 + pl;
        bool ok = (p < n);
        size_t pc = ok ? (size_t)p : (size_t)(n - 1);
        const float* fr = feat + pc * NDIM + 4 * h0;
        float4 fa = *(const float4*)fr;
        float4 fb = *(const float4*)(fr + 8);
        int lb = lab[pc];
        float s0 = sd[2 * pc];

        float f2p = fa.x*fa.x;
        f2p = fmaf(fa.y, fa.y, f2p); f2p = fmaf(fa.z, fa.z, f2p);
        f2p = fmaf(fa.w, fa.w, f2p); f2p = fmaf(fb.x, fb.x, f2p);
        f2p = fmaf(fb.y, fb.y, f2p); f2p = fmaf(fb.z, fb.z, f2p);
        f2p = fmaf(fb.w, fb.w, f2p);
        float f2 = f2p + __shfl_xor(f2p, 32);

        short8v B = { f2bf_rn(fa.x), f2bf_rn(fa.y), f2bf_rn(fa.z), f2bf_rn(fa.w),
                      f2bf_rn(fb.x), f2bf_rn(fb.y), f2bf_rn(fb.z), f2bf_rn(fb.w) };
        f32x16 dz = {};
        f32x16 D = __builtin_amdgcn_mfma_f32_32x32x16_bf16(A, B, dz, 0, 0, 0);

        float mask = ok ? 1.f : 0.f;
        int lb4 = lb - 4 * h0;     // own iff lb4 == (r&3)+8*(r>>2)
        #pragma unroll
        for (int r = 0; r < 16; ++r) {
            const int CR = (r & 3) + 8 * (r >> 2);
            float dot = D[r];
            float q = fmaxf(fmaf(-c2r[r], dot, fmaf(f2, ivr[r], ar[r])), 0.f);
            float P = __expf(-q);
            float ts = fmaf(P * P, fmaf(P, fmaf(P, 0.25f, 0.33333333f), 0.5f), P);
            if (P > 0.5f) ts = -__logf(1.0f - P);
            bool own = (lb4 == CR);
            float contrib = fminf(own ? q : ts, 100.f);
            bce = fmaf(mask, contrib, bce);
            float e = P - s0;
            float sm = own ? mask : 0.f;
            sl = fmaf(sm * e, e, sl);
        }
    }

    __shared__ float rb[256], rsd[256];
    rb[tid] = bce; rsd[tid] = sl;
    __syncthreads();
    for (int s = 128; s > 0; s >>= 1) {
        if (tid < s) { rb[tid] += rb[tid + s]; rsd[tid] += rsd[tid + s]; }
        __syncthreads();
    }
    if (tid == 0) {
        float2 pr; pr.x = rb[0]; pr.y = rsd[0];
        ((float2*)(ws + PMAIN))[blockIdx.x] = pr;
    }
}

__global__ __launch_bounds__(1024)
void k_final(const float* __restrict__ ws, float* __restrict__ out, int n)
{
    __shared__ float rb[NBM], rs[NBM];
    int tid = threadIdx.x;
    float2 p = ((const float2*)(ws + PMAIN))[tid];
    rb[tid] = p.x; rs[tid] = p.y;
    __syncthreads();
    for (int s = NBM / 2; s > 0; s >>= 1) {
        if (tid < s) { rb[tid] += rb[tid + s]; rs[tid] += rs[tid + s]; }
        __syncthreads();
    }
    if (tid == 0) {
        float var_loss  = rb[0] / ((float)n * (float)NCLU);
        float seed_loss = rs[0] / (float)n;
        out[0] = W_VAR * var_loss + ws[G_SMALL] + W_SEED * seed_loss;
    }
}

extern "C" void kernel_launch(void* const* d_in, const int* in_sizes, int n_in,
                              void* d_out, int out_size, void* d_ws, size_t ws_size,
                              hipStream_t stream)
{
    const float* feat = (const float*)d_in[0];
    const float* sd   = (const float*)d_in[1];
    const int*   lab  = (const int*)d_in[2];
    float* ws = (float*)d_ws;
    int n = in_sizes[2];

    k_seg  <<<NBS, 256,  0, stream>>>(feat, sd, lab, ws, n);
    k_red1 <<<152, 256,  0, stream>>>(ws);
    k_stats<<<1,   1024, 0, stream>>>(ws);
    k_main <<<NBM, 256,  0, stream>>>(feat, sd, lab, ws, n);
    k_final<<<1,   NBM,  0, stream>>>(ws, (float*)d_out, n);
}

// Round 9
// 53.917 us; speedup vs baseline: 4.7143x; 1.1101x over previous
//
#include <hip/hip_runtime.h>
#include <hip/hip_bf16.h>

#define NCLU 32
#define NDIM 16
#define W_VAR 3.0f
#define W_DIST 1.0f
#define W_REG 0.001f
#define W_SMOOTH 5.0f
#define W_SEED 5.0f

#define NBS 512                 // k_seg blocks
#define NBM 2048                // k_main blocks
#define SEG_STRIDE 640          // floats per k_seg block partial slice (608 used)
#define PST     (NBS * SEG_STRIDE)
#define G_CM    (PST)           // 512 floats: cluster means
#define G_M2    (PST + 512)     // 32: |mean|^2
#define G_IV    (PST + 544)     // 32: +1/(2 var)
#define G_SMALL (PST + 576)     // 1: dist+reg+smooth (weighted)
#define G_SUMS  (PST + 608)     // 608: reduced segment sums
#define PMAIN   (PST + 1280)    // float2[NBM] main partials

typedef __attribute__((ext_vector_type(8)))  short short8v;
typedef __attribute__((ext_vector_type(16))) float f32x16;

__device__ __forceinline__ short f2bf_rz(float x) {
    return (short)(__float_as_uint(x) >> 16);
}
__device__ __forceinline__ unsigned f2bf_rn_u(float x) {
    unsigned u = __float_as_uint(x);
    u += 0x7FFF + ((u >> 16) & 1);
    return u >> 16;
}

union BPack { short8v s8; unsigned u4[4]; __hip_bfloat162 h[4]; };

// ---------------- k_seg: segment sums as MFMA GEMM  S = V^T x Y ----------------
#define NW 4
__global__ __launch_bounds__(256)
void k_seg(const float* __restrict__ feat, const float* __restrict__ sd,
           const int* __restrict__ lab, float* __restrict__ ws, int n)
{
    __shared__ short sm[NW * 4096];   // per wave: [0,2048) V^T, [2048,4096) Y^T
    int tid = threadIdx.x, wid = tid >> 6, lane = tid & 63;
    short* vt = sm + wid * 4096;
    short* yt = vt + 2048;
    int h0 = lane >> 5, m = lane & 31;
    int rowm = m * 64;
    int csig = (lane & 0x33) | ((lane & 4) << 1) | ((lane & 8) >> 1);

    {
        int4 z = {0, 0, 0, 0};
        int4* yz = (int4*)yt;
        yz[lane] = z; yz[lane + 64] = z; yz[lane + 128] = z; yz[lane + 192] = z;
        vt[18 * 64 + (csig ^ ((18 & 7) << 3))] = (short)0x3F80;
    }

    f32x16 acc = {};
    int nwin = (n + 63) >> 6;
    int wslot = blockIdx.x * NW + wid, nws = gridDim.x * NW;
    int prev = -1;

    for (int w = wslot; w < nwin; w += nws) {
        int p = w * 64 + lane;
        bool ok = (p < n);
        size_t pc = ok ? (size_t)p : (size_t)(n - 1);
        const float4* fp = (const float4*)(feat + pc * NDIM);
        float4 f0 = fp[0], f1 = fp[1], f2 = fp[2], f3 = fp[3];
        float sy = sd[2 * pc + 1];
        int lb = lab[pc];
        float v = __expf(sy);

        if (prev >= 0) yt[prev * 64 + (csig ^ ((prev & 7) << 3))] = 0;
        if (ok)        yt[lb * 64 + (csig ^ ((lb & 7) << 3))] = (short)0x3F80;
        prev = ok ? lb : -1;

        float ff[16] = { f0.x,f0.y,f0.z,f0.w, f1.x,f1.y,f1.z,f1.w,
                         f2.x,f2.y,f2.z,f2.w, f3.x,f3.y,f3.z,f3.w };
        #pragma unroll
        for (int j = 0; j < 16; ++j)
            vt[j * 64 + (csig ^ ((j & 7) << 3))] = f2bf_rz(ff[j]);
        vt[16 * 64 + (csig ^ ((16 & 7) << 3))] = (short)f2bf_rn_u(v);
        vt[17 * 64 + (csig ^ ((17 & 7) << 3))] = (short)f2bf_rn_u(v * v);

        #pragma unroll
        for (int q = 0; q < 4; ++q) {
            int o = rowm + ((8 * h0 + 16 * q) ^ ((m & 7) << 3));
            short8v A = *(short8v*)(vt + o);
            short8v B = *(short8v*)(yt + o);
            acc = __builtin_amdgcn_mfma_f32_32x32x16_bf16(A, B, acc, 0, 0, 0);
        }
    }

    __syncthreads();
    float* fsm = (float*)sm;   // [wid][lane][16]
    #pragma unroll
    for (int r = 0; r < 16; ++r) fsm[wid * 1024 + lane * 16 + r] = acc[r];
    __syncthreads();
    for (int o = tid; o < NCLU * 19; o += 256) {
        int c = o / 19, j = o % 19;
        int hh = (j >> 2) & 1, r = (j & 3) + 4 * (j >> 3);
        int ln = c + 32 * hh;
        float s = 0.f;
        #pragma unroll
        for (int ww = 0; ww < NW; ++ww) s += fsm[ww * 1024 + ln * 16 + r];
        ws[(size_t)blockIdx.x * SEG_STRIDE + o] = s;
    }
}

// ---------------- k_red1: parallel reduce of per-block partials ----------------
__global__ __launch_bounds__(256)
void k_red1(float* __restrict__ ws)
{
    __shared__ float red[256];
    int tid = threadIdx.x;
    int o = blockIdx.x * 4 + (tid & 3);    // 152 blocks x 4 outputs = 608
    int brow = tid >> 2;                   // 64 rows
    float s = 0.f;
    #pragma unroll
    for (int k = 0; k < 8; ++k)
        s += ws[(size_t)(brow + 64 * k) * SEG_STRIDE + o];
    red[tid] = s;
    __syncthreads();
    for (int st = 128; st >= 4; st >>= 1) {
        if (tid < st) red[tid] += red[tid + st];
        __syncthreads();
    }
    if (tid < 4) ws[G_SUMS + blockIdx.x * 4 + tid] = red[tid];
}

// ---------------- k_stats: cluster stats + small losses ----------------
__global__ __launch_bounds__(1024)
void k_stats(float* __restrict__ ws)
{
    __shared__ float sums[NCLU * 19];
    __shared__ float s_cm[NCLU * NDIM];
    __shared__ float red[1024];
    int tid = threadIdx.x;
    if (tid < NCLU * 19) sums[tid] = ws[G_SUMS + tid];
    __syncthreads();

    float contrib = 0.f;
    if (tid < NCLU) {
        int c = tid;
        float cnt = sums[c * 19 + 18];
        float inv = 1.0f / cnt;
        float var = sums[c * 19 + 16] * inv;
        float smo = sums[c * 19 + 17] * inv - var * var;   // mean((v-var)^2)
        float m2 = 0.f;
        for (int d = 0; d < NDIM; ++d) {
            float cm = sums[c * 19 + d] * inv;
            ws[G_CM + c * NDIM + d] = cm;
            s_cm[c * NDIM + d] = cm;
            m2 = fmaf(cm, cm, m2);
        }
        ws[G_M2 + c] = m2;
        ws[G_IV + c] = 0.5f / var;
        contrib = W_REG * sqrtf(m2) * (1.0f / NCLU) + W_SMOOTH * smo * (1.0f / NCLU);
    }
    __syncthreads();
    int i = tid >> 5, j = tid & 31;
    if (i != j) {
        float d2 = 0.f;
        for (int d = 0; d < NDIM; ++d) {
            float df = s_cm[i * NDIM + d] - s_cm[j * NDIM + d];
            d2 = fmaf(df, df, d2);
        }
        float dd = sqrtf(d2);
        float h = fmaxf(3.0f - dd, 0.f);   // 2*DELTA_DIST
        contrib += W_DIST * h * h * (1.0f / ((NCLU - 1) * NCLU));
    }
    red[tid] = contrib;
    __syncthreads();
    for (int s = 512; s > 0; s >>= 1) {
        if (tid < s) red[tid] += red[tid + s];
        __syncthreads();
    }
    if (tid == 0) ws[G_SMALL] = red[0];
}

// ---------------- k_main: BCE + seed. D = q2 directly via augmented MFMA ------
// A1 row c: -2*s_c*cm[c][d]  (s_c = iv_c*log2e).  A2 row c: [m2_c*s_c, s_c, 0..].
// B1 col p: f[p][d].          B2 col p: [1, f2_p, 0..].
// D[c][p] = s_c*(f2 + m2 - 2 dot) = q2 (log2 units). Lane owns point pl=lane&31,
// clusters CR+4*h0, CR=(r&3)+8*(r>>2) = {x in [0,31]: bit2==0}.
__global__ __launch_bounds__(256, 4)
void k_main(const float* __restrict__ feat, const float* __restrict__ sd,
            const int* __restrict__ lab, float* __restrict__ ws, int n)
{
    int tid = threadIdx.x, wid = tid >> 6, lane = tid & 63;
    int h0 = lane >> 5, pl = lane & 31;

    // loop-invariant A fragments (per lane: cluster row m = pl)
    float iv = ws[G_IV + pl];
    float sc = iv * 1.44269504f;           // log2e / (2 var)
    float m2 = ws[G_M2 + pl];
    const float* cmrow = ws + G_CM + pl * NDIM + 4 * h0;
    float4 ca = *(const float4*)(cmrow);
    float4 cb = *(const float4*)(cmrow + 8);
    float t2s = -2.0f * sc;
    BPack a1;
    a1.u4[0] = f2bf_rn_u(ca.x * t2s) | (f2bf_rn_u(ca.y * t2s) << 16);
    a1.u4[1] = f2bf_rn_u(ca.z * t2s) | (f2bf_rn_u(ca.w * t2s) << 16);
    a1.u4[2] = f2bf_rn_u(cb.x * t2s) | (f2bf_rn_u(cb.y * t2s) << 16);
    a1.u4[3] = f2bf_rn_u(cb.z * t2s) | (f2bf_rn_u(cb.w * t2s) << 16);
    BPack a2;
    a2.u4[0] = (h0 == 0) ? (f2bf_rn_u(m2 * sc) | (f2bf_rn_u(sc) << 16)) : 0u;
    a2.u4[1] = 0u; a2.u4[2] = 0u; a2.u4[3] = 0u;

    float bce = 0.f, sl = 0.f;
    int nt = (n + 31) >> 5;
    int slot = blockIdx.x * 4 + wid, nslots = gridDim.x * 4;

    for (int t = slot; t < nt; t += nslots) {
        int p = t * 32 + pl;
        bool ok = (p < n);
        size_t pc = ok ? (size_t)p : (size_t)(n - 1);
        const float* fr = feat + pc * NDIM + 4 * h0;
        float4 fa = *(const float4*)fr;
        float4 fb = *(const float4*)(fr + 8);
        int lb = lab[pc];
        float s0 = sd[2 * pc];

        float f2p = fa.x * fa.x;
        f2p = fmaf(fa.y, fa.y, f2p); f2p = fmaf(fa.z, fa.z, f2p);
        f2p = fmaf(fa.w, fa.w, f2p); f2p = fmaf(fb.x, fb.x, f2p);
        f2p = fmaf(fb.y, fb.y, f2p); f2p = fmaf(fb.z, fb.z, f2p);
        f2p = fmaf(fb.w, fb.w, f2p);
        float f2 = f2p + __shfl_xor(f2p, 32);

        BPack b1;
        float2 q01; q01.x = fa.x; q01.y = fa.y;
        float2 q23; q23.x = fa.z; q23.y = fa.w;
        float2 q45; q45.x = fb.x; q45.y = fb.y;
        float2 q67; q67.x = fb.z; q67.y = fb.w;
        b1.h[0] = __float22bfloat162_rn(q01);
        b1.h[1] = __float22bfloat162_rn(q23);
        b1.h[2] = __float22bfloat162_rn(q45);
        b1.h[3] = __float22bfloat162_rn(q67);
        BPack b2;
        b2.u4[0] = (h0 == 0) ? (0x3F80u | (f2bf_rn_u(f2) << 16)) : 0u;
        b2.u4[1] = 0u; b2.u4[2] = 0u; b2.u4[3] = 0u;

        f32x16 dz = {};
        f32x16 D = __builtin_amdgcn_mfma_f32_32x32x16_bf16(a1.s8, b1.s8, dz, 0, 0, 0);
        D = __builtin_amdgcn_mfma_f32_32x32x16_bf16(a2.s8, b2.s8, D, 0, 0, 0);

        int lb4 = lb - 4 * h0;     // own iff lb4 == (r&3)+8*(r>>2)
        // this lane's r-set covers cluster rows {x: bit2==0}+4*h0: own cluster
        // present here iff lb4 in [0,32) with bit2 clear (exactly one of the
        // two half-lanes holding this point satisfies this).
        unsigned ulb4 = (unsigned)lb4;
        bool hasown = (ulb4 < 32u) && ((ulb4 & 4u) == 0u);
        float bce_t = 0.f, ownP = 0.f;
        #pragma unroll
        for (int r = 0; r < 16; ++r) {
            const int CR = (r & 3) + 8 * (r >> 2);
            float q2 = fmaxf(D[r], 0.f);
            float P = __builtin_amdgcn_exp2f(-q2);
            float ts = fmaf(P * P, fmaf(P, fmaf(P, 0.25f, 0.33333333f), 0.5f), P);
            if (P > 0.5f) ts = -__logf(1.0f - P);
            bool own = (lb4 == CR);
            float contrib = fminf(own ? q2 * 0.69314718f : ts, 100.f);
            bce_t += contrib;
            ownP = own ? P : ownP;
        }
        float mask = ok ? 1.f : 0.f;
        bce = fmaf(mask, bce_t, bce);
        float e = ownP - s0;
        float smk = (hasown ? mask : 0.f);
        sl = fmaf(smk * e, e, sl);
    }

    __shared__ float rb[256], rsd[256];
    rb[tid] = bce; rsd[tid] = sl;
    __syncthreads();
    for (int s = 128; s > 0; s >>= 1) {
        if (tid < s) { rb[tid] += rb[tid + s]; rsd[tid] += rsd[tid + s]; }
        __syncthreads();
    }
    if (tid == 0) {
        float2 pr; pr.x = rb[0]; pr.y = rsd[0];
        ((float2*)(ws + PMAIN))[blockIdx.x] = pr;
    }
}

__global__ __launch_bounds__(1024)
void k_final(const float* __restrict__ ws, float* __restrict__ out, int n)
{
    __shared__ float rb[1024], rs[1024];
    int tid = threadIdx.x;
    float2 p0 = ((const float2*)(ws + PMAIN))[tid];
    float2 p1 = ((const float2*)(ws + PMAIN))[tid + 1024];
    rb[tid] = p0.x + p1.x; rs[tid] = p0.y + p1.y;
    __syncthreads();
    for (int s = 512; s > 0; s >>= 1) {
        if (tid < s) { rb[tid] += rb[tid + s]; rs[tid] += rs[tid + s]; }
        __syncthreads();
    }
    if (tid == 0) {
        float var_loss  = rb[0] / ((float)n * (float)NCLU);
        float seed_loss = rs[0] / (float)n;
        out[0] = W_VAR * var_loss + ws[G_SMALL] + W_SEED * seed_loss;
    }
}

extern "C" void kernel_launch(void* const* d_in, const int* in_sizes, int n_in,
                              void* d_out, int out_size, void* d_ws, size_t ws_size,
                              hipStream_t stream)
{
    const float* feat = (const float*)d_in[0];
    const float* sd   = (const float*)d_in[1];
    const int*   lab  = (const int*)d_in[2];
    float* ws = (float*)d_ws;
    int n = in_sizes[2];

    k_seg  <<<NBS, 256,  0, stream>>>(feat, sd, lab, ws, n);
    k_red1 <<<152, 256,  0, stream>>>(ws);
    k_stats<<<1,   1024, 0, stream>>>(ws);
    k_main <<<NBM, 256,  0, stream>>>(feat, sd, lab, ws, n);
    k_final<<<1,   1024, 0, stream>>>(ws, (float*)d_out, n);
}